// Round 7
// baseline (301.517 us; speedup 1.0000x reference)
//
#include <hip/hip_runtime.h>
#include <hip/hip_bf16.h>
#include <math.h>

constexpr int kBS = 2;
constexpr int kNQ = 20197;
constexpr int kNV = 20197;
constexpr int kM  = kBS * kNQ;   // 40394
constexpr int kMT = 632;         // 64-row m-tiles (40448 rows incl. slack)
constexpr int kMpad = kMT * 64;  // 40448

__constant__ int cLH[4] = {100, 50, 25, 13};
__constant__ int cLW[4] = {152, 76, 38, 19};
__constant__ int cLS[4] = {0, 15200, 19000, 19950};

typedef __bf16 bf16x8 __attribute__((ext_vector_type(8)));
typedef float  f32x4  __attribute__((ext_vector_type(4)));
typedef float  f32x2  __attribute__((ext_vector_type(2)));

__device__ __forceinline__ unsigned short f2bf(float x) {
    unsigned u = __float_as_uint(x);
    return (unsigned short)((u + 0x7fffu + ((u >> 16) & 1u)) >> 16);
}
__device__ __forceinline__ unsigned pack2(float a, float b) {
    return (unsigned)f2bf(a) | ((unsigned)f2bf(b) << 16);
}
__device__ __forceinline__ float bflo(unsigned u) { return __uint_as_float(u << 16); }
__device__ __forceinline__ float bfhi(unsigned u) { return __uint_as_float(u & 0xffff0000u); }
__device__ __forceinline__ void gload_lds16(const void* g, void* s) {
    __builtin_amdgcn_global_load_lds(
        (const __attribute__((address_space(1))) void*)g,
        (__attribute__((address_space(3))) void*)s, 16, 0, 0);
}

// ---------------------------------------------------------------------------
// prep_w: weight transposes (fp32 KxN -> bf16 NxK) + fused bias384.
// ---------------------------------------------------------------------------
__global__ __launch_bounds__(256) void prep_w(
    const float* __restrict__ Wv, const float* __restrict__ Wso,
    const float* __restrict__ Waw, const float* __restrict__ Wo,
    const float* __restrict__ bso, const float* __restrict__ baw,
    unsigned short* __restrict__ WvT, unsigned short* __restrict__ WsoawT,
    unsigned short* __restrict__ WoT, float* __restrict__ bias384)
{
    int k = blockIdx.x * 256 + threadIdx.x;
    if (k < 65536) { int kk = k >> 8, n = k & 255; WvT[n * 256 + kk] = f2bf(Wv[k]); return; }
    k -= 65536;
    if (k < 65536) { int kk = k >> 8, n = k & 255; WsoawT[n * 256 + kk] = f2bf(Wso[k]); return; }
    k -= 65536;
    if (k < 32768) { int kk = k >> 7, n = k & 127; WsoawT[(256 + n) * 256 + kk] = f2bf(Waw[k]); return; }
    k -= 32768;
    if (k < 65536) { int kk = k >> 8, n = k & 255; WoT[n * 256 + kk] = f2bf(Wo[k]); return; }
    k -= 65536;
    if (k < 384) bias384[k] = (k < 256) ? bso[k] : baw[k - 256];
}

// ---------------------------------------------------------------------------
// gemm_core (used by gemm_dual only): r6-proven structure — __syncthreads per
// chunk, 2x8KB swizzled B panels via global_load_lds, pitch-264 As, swapped
// MFMA operands + vectorized epilogue, 3 blocks/CU.
// ---------------------------------------------------------------------------
template<int CFP32>
__device__ __forceinline__ void gemm_core(
    const void* __restrict__ Av, const __hip_bfloat16* __restrict__ BT,
    const float* __restrict__ bias, const float* __restrict__ res,
    int N, int NT, void* __restrict__ Cv, int m0)
{
    __shared__ __hip_bfloat16 As[64 * 264];      // ~33 KB, pitch 264
    __shared__ __hip_bfloat16 Bs[2][128 * 32];   // 2 x 8 KB

    const int t = threadIdx.x;
    const int wave = t >> 6, lane = t & 63;
    const int quad = lane >> 4, l16 = lane & 15;
    const int mw = (wave & 1) * 32, nw = (wave >> 1) * 64;

    auto issueB = [&](int nti, int kc, int buf) {
        #pragma unroll
        for (int j = 0; j < 2; ++j) {
            int s = j * 256 + t;
            int row = s >> 2;
            int ql = (s & 3) ^ ((row >> 1) & 3);
            gload_lds16((const char*)BT + (size_t)(nti * 128 + row) * 512
                            + kc * 64 + ql * 16,
                        (char*)&Bs[buf][0] + s * 16);
        }
    };

    issueB(0, 0, 0);   // first B panel in flight during A staging

    {
        const float* af = (const float*)Av;
        #pragma unroll
        for (int p = 0; p < 16; ++p) {
            int idx = p * 256 + t;
            int row = idx >> 6, col4 = idx & 63;
            float4 f = make_float4(0.f, 0.f, 0.f, 0.f);
            if (m0 + row < kM)
                f = *(const float4*)(af + (size_t)(m0 + row) * 256 + col4 * 4);
            uint2 u = make_uint2(pack2(f.x, f.y), pack2(f.z, f.w));
            *(uint2*)(void*)&As[row * 264 + col4 * 4] = u;
        }
    }

    for (int nti = 0; nti < NT; ++nti) {
        f32x4 acc[2][4] = {};
        for (int kc = 0; kc < 8; ++kc) {
            __syncthreads();     // drains current B panel (+ A stage on iter 0)
            if (kc < 7)             issueB(nti, kc + 1, (kc + 1) & 1);
            else if (nti + 1 < NT)  issueB(nti + 1, 0, 0);
            bf16x8 afr[2], bfr[4];
            #pragma unroll
            for (int mt = 0; mt < 2; ++mt)
                afr[mt] = *(const bf16x8*)(const void*)
                    &As[(mw + mt * 16 + l16) * 264 + kc * 32 + quad * 8];
            #pragma unroll
            for (int nt = 0; nt < 4; ++nt) {
                int r = nw + nt * 16 + l16;
                int qp = quad ^ ((r >> 1) & 3);          // swizzled slot
                bfr[nt] = *(const bf16x8*)(const void*)
                    &Bs[kc & 1][r * 32 + qp * 8];
            }
            // SWAPPED operands: D row index = B rows (n), col index = A rows (m)
            #pragma unroll
            for (int mt = 0; mt < 2; ++mt)
                #pragma unroll
                for (int nt = 0; nt < 4; ++nt)
                    acc[mt][nt] = __builtin_amdgcn_mfma_f32_16x16x32_bf16(
                        bfr[nt], afr[mt], acc[mt][nt], 0, 0, 0);
        }
        // epilogue: lane holds cols n0..n0+3 (n0 = ...+quad*4) at row ...+l16
        const int n0g = nti * 128;
        #pragma unroll
        for (int nt = 0; nt < 4; ++nt) {
            int n0 = n0g + nw + nt * 16 + quad * 4;
            float4 b4 = *(const float4*)&bias[n0];
            #pragma unroll
            for (int mt = 0; mt < 2; ++mt) {
                int row = m0 + mw + mt * 16 + l16;
                if (row < kM) {
                    f32x4 a = acc[mt][nt];
                    if (CFP32) {
                        float4 r4 = *(const float4*)(res + (size_t)row * N + n0);
                        float4 o;
                        o.x = a[0] + b4.x + r4.x;
                        o.y = a[1] + b4.y + r4.y;
                        o.z = a[2] + b4.z + r4.z;
                        o.w = a[3] + b4.w + r4.w;
                        *(float4*)((float*)Cv + (size_t)row * N + n0) = o;
                    } else {
                        uint2 u = make_uint2(pack2(a[0] + b4.x, a[1] + b4.y),
                                             pack2(a[2] + b4.z, a[3] + b4.w));
                        *(uint2*)((unsigned short*)Cv + (size_t)row * N + n0) = u;
                    }
                }
            }
        }
    }
}

// bx=0: v_b = value @ WvT^T + bv; bx=1: soaw = query @ WsoawT^T + bias384
__global__ __launch_bounds__(256, 3) void gemm_dual(
    const float* __restrict__ value, const __hip_bfloat16* __restrict__ WvT,
    const float* __restrict__ bv, unsigned short* __restrict__ v_b,
    const float* __restrict__ query, const __hip_bfloat16* __restrict__ WsoawT,
    const float* __restrict__ b384, unsigned short* __restrict__ soaw)
{
    const int m0 = blockIdx.y * 64;
    const float* A; const __hip_bfloat16* BT; const float* bias;
    unsigned short* C; int N, NT;
    if (blockIdx.x == 0) { A = value; BT = WvT;    bias = bv;   C = v_b;  N = 256; NT = 2; }
    else                 { A = query; BT = WsoawT; bias = b384; C = soaw; N = 384; NT = 3; }
    gemm_core<0>(A, BT, bias, nullptr, N, NT, C, m0);
}

// ---------------------------------------------------------------------------
// gemm_final: out = mid_b(bf16) @ WoT^T + bo + query (fp32 out).
// NEW: A lives in REGISTERS (16 x uint4 = 64 VGPR per lane; bf16 A needs no
// conversion) — no As LDS, no A-stage, chunk body loses 2 of 6 ds_read_b128.
// Sync structure unchanged from the proven __syncthreads loop (first barrier
// also drains the A gloads via its vmcnt(0)). LDS = 16 KB (B panels only);
// occupancy capped by VGPR at 3 blocks/CU (launch_bounds 256,3 — no spill).
// ---------------------------------------------------------------------------
__global__ __launch_bounds__(256, 3) void gemm_final(
    const unsigned short* __restrict__ mid_b, const __hip_bfloat16* __restrict__ WoT,
    const float* __restrict__ bo, const float* __restrict__ query,
    float* __restrict__ out)
{
    constexpr int N = 256, NT = 2;
    const int m0 = blockIdx.y * 64;

    __shared__ __hip_bfloat16 Bs[2][128 * 32];   // 2 x 8 KB

    const int t = threadIdx.x;
    const int wave = t >> 6, lane = t & 63;
    const int quad = lane >> 4, l16 = lane & 15;
    const int mw = (wave & 1) * 32, nw = (wave >> 1) * 64;

    auto issueB = [&](int nti, int kc, int buf) {
        #pragma unroll
        for (int j = 0; j < 2; ++j) {
            int s = j * 256 + t;
            int row = s >> 2;
            int ql = (s & 3) ^ ((row >> 1) & 3);
            gload_lds16((const char*)WoT + (size_t)(nti * 128 + row) * 512
                            + kc * 64 + ql * 16,
                        (char*)&Bs[buf][0] + s * 16);
        }
    };

    issueB(0, 0, 0);

    // A fragments straight to registers: lane (quad,l16) needs rows
    // m0+mw+mt*16+l16, bytes [kc*64 + quad*16, +16). Rows < kMpad always
    // (slack rows hold garbage but only poison guarded output rows).
    bf16x8 areg[2][8];
    #pragma unroll
    for (int mt = 0; mt < 2; ++mt)
        #pragma unroll
        for (int kc = 0; kc < 8; ++kc)
            areg[mt][kc] = *(const bf16x8*)(const void*)
                (mid_b + (size_t)(m0 + mw + mt * 16 + l16) * 256 + kc * 32 + quad * 8);

    for (int nti = 0; nti < NT; ++nti) {
        f32x4 acc[2][4] = {};
        for (int kc = 0; kc < 8; ++kc) {
            __syncthreads();     // drains current B panel (+ A gloads on iter 0)
            if (kc < 7)             issueB(nti, kc + 1, (kc + 1) & 1);
            else if (nti + 1 < NT)  issueB(nti + 1, 0, 0);
            bf16x8 bfr[4];
            #pragma unroll
            for (int nt = 0; nt < 4; ++nt) {
                int r = nw + nt * 16 + l16;
                int qp = quad ^ ((r >> 1) & 3);
                bfr[nt] = *(const bf16x8*)(const void*)
                    &Bs[kc & 1][r * 32 + qp * 8];
            }
            #pragma unroll
            for (int mt = 0; mt < 2; ++mt)
                #pragma unroll
                for (int nt = 0; nt < 4; ++nt)
                    acc[mt][nt] = __builtin_amdgcn_mfma_f32_16x16x32_bf16(
                        bfr[nt], areg[mt][kc], acc[mt][nt], 0, 0, 0);
        }
        const int n0g = nti * 128;
        #pragma unroll
        for (int nt = 0; nt < 4; ++nt) {
            int n0 = n0g + nw + nt * 16 + quad * 4;
            float4 b4 = *(const float4*)&bo[n0];
            #pragma unroll
            for (int mt = 0; mt < 2; ++mt) {
                int row = m0 + mw + mt * 16 + l16;
                if (row < kM) {
                    f32x4 a = acc[mt][nt];
                    float4 r4 = *(const float4*)(query + (size_t)row * N + n0);
                    float4 o;
                    o.x = a[0] + b4.x + r4.x;
                    o.y = a[1] + b4.y + r4.y;
                    o.z = a[2] + b4.z + r4.z;
                    o.w = a[3] + b4.w + r4.w;
                    *(float4*)(out + (size_t)row * N + n0) = o;
                }
            }
        }
    }
}

// ---------------------------------------------------------------------------
// Sampler v3: one WAVE per query (2 queries per 128-thr block).
// Lane l: head h = l>>3, 4 channels c0 = (l&7)*4 -> dwordx2 gathers.
// Per-query VMEM/LDS instruction count HALVES vs v2 (4096 vs 8192); VALU
// lane-ops drop ~40% (fixed per-gather overhead amortized over 4 channels).
// Phase 1: lane computes units u0=2l, u1=2l+1 (same (h,l,p) numbering as
// before); softmax over 16 units = 2 local + shfl_xor{4,2,1} across the
// 8-lane head group. LDS sC[wave][corner][unit] so phase-1 stores are dense
// per-lane int4 writes and phase-2 reads are 8-lane broadcasts.
// ---------------------------------------------------------------------------
struct C4 { int o[4]; float w[4]; };

__device__ __forceinline__ C4 mk_corners(float rx, float ry, float sx, float sy,
                                         float wgt, int lv, int h)
{
    C4 r;
    const int ww = cLW[lv], hh = cLH[lv];
    float x = rx * (float)ww + sx - 0.5f;
    float y = ry * (float)hh + sy - 0.5f;
    float xf = floorf(x), yf = floorf(y);
    int x0 = (int)xf, y0 = (int)yf;
    float wx1 = x - xf, wx0 = 1.f - wx1;
    float wy1 = y - yf, wy0 = 1.f - wy1;
    bool vx0 = (x0 >= 0) & (x0 < ww);
    bool vx1 = (x0 >= -1) & (x0 + 1 < ww);
    bool vy0 = (y0 >= 0) & (y0 < hh);
    bool vy1 = (y0 >= -1) & (y0 + 1 < hh);
    int cx0 = min(max(x0, 0), ww - 1);
    int cx1 = min(max(x0 + 1, 0), ww - 1);
    int cy0 = min(max(y0, 0), hh - 1);
    int cy1 = min(max(y0 + 1, 0), hh - 1);
    const int base2 = cLS[lv] * 512 + h * 64;                // BYTE offsets
    r.o[0] = base2 + (cy0 * ww + cx0) * 512; r.w[0] = (vx0 & vy0) ? wgt * wx0 * wy0 : 0.f;
    r.o[1] = base2 + (cy0 * ww + cx1) * 512; r.w[1] = (vx1 & vy0) ? wgt * wx1 * wy0 : 0.f;
    r.o[2] = base2 + (cy1 * ww + cx0) * 512; r.w[2] = (vx0 & vy1) ? wgt * wx0 * wy1 : 0.f;
    r.o[3] = base2 + (cy1 * ww + cx1) * 512; r.w[3] = (vx1 & vy1) ? wgt * wx1 * wy1 : 0.f;
    return r;
}

__global__ __launch_bounds__(128) void msda_sample(
    const __hip_bfloat16* __restrict__ v,     // (BS*NV, 256) bf16
    const __hip_bfloat16* __restrict__ soaw,  // (M, 384) bf16: so | logits
    const float* __restrict__ rp,             // (M, 4, 2)
    __hip_bfloat16* __restrict__ mid)         // (kMpad, 256) bf16
{
    const int wv = threadIdx.x >> 6;          // wave -> query
    const int l  = threadIdx.x & 63;
    const int bq = blockIdx.x * 2 + wv;       // kM even: always < kM
    const int b  = bq >= kNQ;

    __shared__ int2 sC[2][4][130];            // [wave][corner][unit] (+pad)

    {   // phase 1: units u0 = 2l, u1 = 2l+1 (u = h*16 + lp)
        const int u0 = 2 * l;
        const int h  = u0 >> 4;               // same for both units
        const int lv = (u0 & 15) >> 2;        // level, same for both units

        uint2 so2 = *(const uint2*)(const void*)(soaw + (size_t)bq * 384 + 2 * u0);
        unsigned lg2 = *(const unsigned*)(const void*)(soaw + (size_t)bq * 384 + 256 + u0);
        float logit0 = bflo(lg2), logit1 = bfhi(lg2);
        float2 rr = *(const float2*)(rp + (size_t)bq * 8 + lv * 2);

        float mx = fmaxf(logit0, logit1);
        #pragma unroll
        for (int s = 4; s >= 1; s >>= 1) mx = fmaxf(mx, __shfl_xor(mx, s, 8));
        float e0 = __expf(logit0 - mx), e1 = __expf(logit1 - mx);
        float sum = e0 + e1;
        #pragma unroll
        for (int s = 4; s >= 1; s >>= 1) sum += __shfl_xor(sum, s, 8);
        float inv = 1.f / sum;

        C4 ca = mk_corners(rr.x, rr.y, bflo(so2.x), bfhi(so2.x), e0 * inv, lv, h);
        C4 cb = mk_corners(rr.x, rr.y, bflo(so2.y), bfhi(so2.y), e1 * inv, lv, h);
        #pragma unroll
        for (int k2 = 0; k2 < 4; ++k2)
            *(int4*)(void*)&sC[wv][k2][u0] =
                make_int4(ca.o[k2], __float_as_int(ca.w[k2]),
                          cb.o[k2], __float_as_int(cb.w[k2]));
    }
    __syncthreads();

    // phase 2: lane = (head l>>3, channels (l&7)*4 .. +3)
    const int h2 = l >> 3, c0 = (l & 7) * 4;
    const char* vb = (const char*)v + (size_t)b * ((size_t)kNV * 512);  // uniform base
    const unsigned cb2 = (unsigned)(c0 * 2);
    f32x2 acc0 = {0.f, 0.f}, acc1 = {0.f, 0.f};
    const int ub = h2 * 16;
    #pragma unroll 4
    for (int pt = 0; pt < 16; ++pt) {
        #pragma unroll
        for (int k2 = 0; k2 < 4; ++k2) {
            int2 pw = sC[wv][k2][ub + pt];
            float wgt = __int_as_float(pw.y);
            uint2 u2 = *(const uint2*)(const void*)(vb + ((unsigned)pw.x + cb2));
            f32x2 w2; w2.x = wgt; w2.y = wgt;
            f32x2 lo; lo.x = bflo(u2.x); lo.y = bfhi(u2.x);
            f32x2 hi; hi.x = bflo(u2.y); hi.y = bfhi(u2.y);
            acc0 = lo * w2 + acc0;            // ffp-contract -> v_pk_fma_f32
            acc1 = hi * w2 + acc1;
        }
    }
    *(uint2*)(void*)(mid + (size_t)bq * 256 + h2 * 32 + c0) =
        make_uint2(pack2(acc0.x, acc0.y), pack2(acc1.x, acc1.y));
}

// ---------------------------------------------------------------------------
extern "C" void kernel_launch(void* const* d_in, const int* in_sizes, int n_in,
                              void* d_out, int out_size, void* d_ws, size_t ws_size,
                              hipStream_t stream)
{
    const float* query = (const float*)d_in[0];
    const float* value = (const float*)d_in[1];
    const float* rp    = (const float*)d_in[2];
    const float* Wv  = (const float*)d_in[5];
    const float* bv  = (const float*)d_in[6];
    const float* Wso = (const float*)d_in[7];
    const float* bso = (const float*)d_in[8];
    const float* Waw = (const float*)d_in[9];
    const float* baw = (const float*)d_in[10];
    const float* Wo  = (const float*)d_in[11];
    const float* bo  = (const float*)d_in[12];

    // d_out overlay: v_b bf16 (kM*512 B) in first half; dead before the
    // final GEMM rewrites all of d_out.
    unsigned short* v_b = (unsigned short*)d_out;

    // ws: soaw bf16 (kM*384) | mid_b bf16 (kMpad*256) | WvT | WsoawT | WoT | bias384
    char* p = (char*)d_ws;
    __hip_bfloat16* soaw  = (__hip_bfloat16*)p;  p += (size_t)kM * 384 * 2;
    unsigned short* mid_b = (unsigned short*)p;  p += (size_t)kMpad * 256 * 2;
    unsigned short* WvT    = (unsigned short*)p; p += 256 * 256 * 2;
    unsigned short* WsoawT = (unsigned short*)p; p += 384 * 256 * 2;
    unsigned short* WoT    = (unsigned short*)p; p += 256 * 256 * 2;
    float* bias384         = (float*)p;

    hipLaunchKernelGGL(prep_w, dim3(898), dim3(256), 0, stream,
                       Wv, Wso, Waw, Wo, bso, baw, WvT, WsoawT, WoT, bias384);

    hipLaunchKernelGGL(gemm_dual, dim3(2, kMT), dim3(256), 0, stream,
                       value, (const __hip_bfloat16*)WvT, bv, v_b,
                       query, (const __hip_bfloat16*)WsoawT, bias384,
                       (unsigned short*)soaw);

    hipLaunchKernelGGL(msda_sample, dim3(kM / 2), dim3(128), 0, stream,
                       (const __hip_bfloat16*)v_b, soaw, rp, (__hip_bfloat16*)mid_b);

    hipLaunchKernelGGL(gemm_final, dim3(1, kMT), dim3(256), 0, stream,
                       mid_b, (const __hip_bfloat16*)WoT, bo, query, (float*)d_out);
}

// Round 8
// 298.862 us; speedup vs baseline: 1.0089x; 1.0089x over previous
//
#include <hip/hip_runtime.h>
#include <hip/hip_bf16.h>
#include <math.h>

constexpr int kBS = 2;
constexpr int kNQ = 20197;
constexpr int kNV = 20197;
constexpr int kM  = kBS * kNQ;   // 40394
constexpr int kMT = 632;         // 64-row m-tiles (40448 rows incl. slack)
constexpr int kMpad = kMT * 64;  // 40448

__constant__ int cLH[4] = {100, 50, 25, 13};
__constant__ int cLW[4] = {152, 76, 38, 19};
__constant__ int cLS[4] = {0, 15200, 19000, 19950};

typedef __bf16 bf16x8 __attribute__((ext_vector_type(8)));
typedef float  f32x4  __attribute__((ext_vector_type(4)));
typedef float  f32x2  __attribute__((ext_vector_type(2)));

__device__ __forceinline__ unsigned short f2bf(float x) {
    unsigned u = __float_as_uint(x);
    return (unsigned short)((u + 0x7fffu + ((u >> 16) & 1u)) >> 16);
}
__device__ __forceinline__ unsigned pack2(float a, float b) {
    return (unsigned)f2bf(a) | ((unsigned)f2bf(b) << 16);
}
__device__ __forceinline__ float bflo(unsigned u) { return __uint_as_float(u << 16); }
__device__ __forceinline__ float bfhi(unsigned u) { return __uint_as_float(u & 0xffff0000u); }
__device__ __forceinline__ void gload_lds16(const void* g, void* s) {
    __builtin_amdgcn_global_load_lds(
        (const __attribute__((address_space(1))) void*)g,
        (__attribute__((address_space(3))) void*)s, 16, 0, 0);
}

// ---------------------------------------------------------------------------
// prep_w: weight transposes (fp32 KxN -> bf16 NxK) + fused bias384.
// ---------------------------------------------------------------------------
__global__ __launch_bounds__(256) void prep_w(
    const float* __restrict__ Wv, const float* __restrict__ Wso,
    const float* __restrict__ Waw, const float* __restrict__ Wo,
    const float* __restrict__ bso, const float* __restrict__ baw,
    unsigned short* __restrict__ WvT, unsigned short* __restrict__ WsoawT,
    unsigned short* __restrict__ WoT, float* __restrict__ bias384)
{
    int k = blockIdx.x * 256 + threadIdx.x;
    if (k < 65536) { int kk = k >> 8, n = k & 255; WvT[n * 256 + kk] = f2bf(Wv[k]); return; }
    k -= 65536;
    if (k < 65536) { int kk = k >> 8, n = k & 255; WsoawT[n * 256 + kk] = f2bf(Wso[k]); return; }
    k -= 65536;
    if (k < 32768) { int kk = k >> 7, n = k & 127; WsoawT[(256 + n) * 256 + kk] = f2bf(Waw[k]); return; }
    k -= 32768;
    if (k < 65536) { int kk = k >> 8, n = k & 255; WoT[n * 256 + kk] = f2bf(Wo[k]); return; }
    k -= 65536;
    if (k < 384) bias384[k] = (k < 256) ? bso[k] : baw[k - 256];
}

// ---------------------------------------------------------------------------
// gemm_core (used by gemm_dual only): r6-proven structure — __syncthreads per
// chunk, 2x8KB swizzled B panels via global_load_lds, pitch-264 As, swapped
// MFMA operands + vectorized epilogue, 3 blocks/CU.
// ---------------------------------------------------------------------------
template<int CFP32>
__device__ __forceinline__ void gemm_core(
    const void* __restrict__ Av, const __hip_bfloat16* __restrict__ BT,
    const float* __restrict__ bias, const float* __restrict__ res,
    int N, int NT, void* __restrict__ Cv, int m0)
{
    __shared__ __hip_bfloat16 As[64 * 264];      // ~33 KB, pitch 264
    __shared__ __hip_bfloat16 Bs[2][128 * 32];   // 2 x 8 KB

    const int t = threadIdx.x;
    const int wave = t >> 6, lane = t & 63;
    const int quad = lane >> 4, l16 = lane & 15;
    const int mw = (wave & 1) * 32, nw = (wave >> 1) * 64;

    auto issueB = [&](int nti, int kc, int buf) {
        #pragma unroll
        for (int j = 0; j < 2; ++j) {
            int s = j * 256 + t;
            int row = s >> 2;
            int ql = (s & 3) ^ ((row >> 1) & 3);
            gload_lds16((const char*)BT + (size_t)(nti * 128 + row) * 512
                            + kc * 64 + ql * 16,
                        (char*)&Bs[buf][0] + s * 16);
        }
    };

    issueB(0, 0, 0);   // first B panel in flight during A staging

    {
        const float* af = (const float*)Av;
        #pragma unroll
        for (int p = 0; p < 16; ++p) {
            int idx = p * 256 + t;
            int row = idx >> 6, col4 = idx & 63;
            float4 f = make_float4(0.f, 0.f, 0.f, 0.f);
            if (m0 + row < kM)
                f = *(const float4*)(af + (size_t)(m0 + row) * 256 + col4 * 4);
            uint2 u = make_uint2(pack2(f.x, f.y), pack2(f.z, f.w));
            *(uint2*)(void*)&As[row * 264 + col4 * 4] = u;
        }
    }

    for (int nti = 0; nti < NT; ++nti) {
        f32x4 acc[2][4] = {};
        for (int kc = 0; kc < 8; ++kc) {
            __syncthreads();     // drains current B panel (+ A stage on iter 0)
            if (kc < 7)             issueB(nti, kc + 1, (kc + 1) & 1);
            else if (nti + 1 < NT)  issueB(nti + 1, 0, 0);
            bf16x8 afr[2], bfr[4];
            #pragma unroll
            for (int mt = 0; mt < 2; ++mt)
                afr[mt] = *(const bf16x8*)(const void*)
                    &As[(mw + mt * 16 + l16) * 264 + kc * 32 + quad * 8];
            #pragma unroll
            for (int nt = 0; nt < 4; ++nt) {
                int r = nw + nt * 16 + l16;
                int qp = quad ^ ((r >> 1) & 3);          // swizzled slot
                bfr[nt] = *(const bf16x8*)(const void*)
                    &Bs[kc & 1][r * 32 + qp * 8];
            }
            // SWAPPED operands: D row index = B rows (n), col index = A rows (m)
            #pragma unroll
            for (int mt = 0; mt < 2; ++mt)
                #pragma unroll
                for (int nt = 0; nt < 4; ++nt)
                    acc[mt][nt] = __builtin_amdgcn_mfma_f32_16x16x32_bf16(
                        bfr[nt], afr[mt], acc[mt][nt], 0, 0, 0);
        }
        // epilogue: lane holds cols n0..n0+3 (n0 = ...+quad*4) at row ...+l16
        const int n0g = nti * 128;
        #pragma unroll
        for (int nt = 0; nt < 4; ++nt) {
            int n0 = n0g + nw + nt * 16 + quad * 4;
            float4 b4 = *(const float4*)&bias[n0];
            #pragma unroll
            for (int mt = 0; mt < 2; ++mt) {
                int row = m0 + mw + mt * 16 + l16;
                if (row < kM) {
                    f32x4 a = acc[mt][nt];
                    if (CFP32) {
                        float4 r4 = *(const float4*)(res + (size_t)row * N + n0);
                        float4 o;
                        o.x = a[0] + b4.x + r4.x;
                        o.y = a[1] + b4.y + r4.y;
                        o.z = a[2] + b4.z + r4.z;
                        o.w = a[3] + b4.w + r4.w;
                        *(float4*)((float*)Cv + (size_t)row * N + n0) = o;
                    } else {
                        uint2 u = make_uint2(pack2(a[0] + b4.x, a[1] + b4.y),
                                             pack2(a[2] + b4.z, a[3] + b4.w));
                        *(uint2*)((unsigned short*)Cv + (size_t)row * N + n0) = u;
                    }
                }
            }
        }
    }
}

// bx=0: v_b = value @ WvT^T + bv; bx=1: soaw = query @ WsoawT^T + bias384
__global__ __launch_bounds__(256, 3) void gemm_dual(
    const float* __restrict__ value, const __hip_bfloat16* __restrict__ WvT,
    const float* __restrict__ bv, unsigned short* __restrict__ v_b,
    const float* __restrict__ query, const __hip_bfloat16* __restrict__ WsoawT,
    const float* __restrict__ b384, unsigned short* __restrict__ soaw)
{
    const int m0 = blockIdx.y * 64;
    const float* A; const __hip_bfloat16* BT; const float* bias;
    unsigned short* C; int N, NT;
    if (blockIdx.x == 0) { A = value; BT = WvT;    bias = bv;   C = v_b;  N = 256; NT = 2; }
    else                 { A = query; BT = WsoawT; bias = b384; C = soaw; N = 384; NT = 3; }
    gemm_core<0>(A, BT, bias, nullptr, N, NT, C, m0);
}

// ---------------------------------------------------------------------------
// gemm_final: out = mid_b(bf16) @ WoT^T + bo + query (fp32 out).
// A in REGISTERS (16 x uint4/lane, bf16, no conversion) — neutral vs LDS in
// r7 A/B but frees LDS and sheds 2 ds_read_b128 per chunk. Proven passing.
// ---------------------------------------------------------------------------
__global__ __launch_bounds__(256, 3) void gemm_final(
    const unsigned short* __restrict__ mid_b, const __hip_bfloat16* __restrict__ WoT,
    const float* __restrict__ bo, const float* __restrict__ query,
    float* __restrict__ out)
{
    constexpr int N = 256, NT = 2;
    const int m0 = blockIdx.y * 64;

    __shared__ __hip_bfloat16 Bs[2][128 * 32];   // 2 x 8 KB

    const int t = threadIdx.x;
    const int wave = t >> 6, lane = t & 63;
    const int quad = lane >> 4, l16 = lane & 15;
    const int mw = (wave & 1) * 32, nw = (wave >> 1) * 64;

    auto issueB = [&](int nti, int kc, int buf) {
        #pragma unroll
        for (int j = 0; j < 2; ++j) {
            int s = j * 256 + t;
            int row = s >> 2;
            int ql = (s & 3) ^ ((row >> 1) & 3);
            gload_lds16((const char*)WoT + (size_t)(nti * 128 + row) * 512
                            + kc * 64 + ql * 16,
                        (char*)&Bs[buf][0] + s * 16);
        }
    };

    issueB(0, 0, 0);

    bf16x8 areg[2][8];
    #pragma unroll
    for (int mt = 0; mt < 2; ++mt)
        #pragma unroll
        for (int kc = 0; kc < 8; ++kc)
            areg[mt][kc] = *(const bf16x8*)(const void*)
                (mid_b + (size_t)(m0 + mw + mt * 16 + l16) * 256 + kc * 32 + quad * 8);

    for (int nti = 0; nti < NT; ++nti) {
        f32x4 acc[2][4] = {};
        for (int kc = 0; kc < 8; ++kc) {
            __syncthreads();     // drains current B panel (+ A gloads on iter 0)
            if (kc < 7)             issueB(nti, kc + 1, (kc + 1) & 1);
            else if (nti + 1 < NT)  issueB(nti + 1, 0, 0);
            bf16x8 bfr[4];
            #pragma unroll
            for (int nt = 0; nt < 4; ++nt) {
                int r = nw + nt * 16 + l16;
                int qp = quad ^ ((r >> 1) & 3);
                bfr[nt] = *(const bf16x8*)(const void*)
                    &Bs[kc & 1][r * 32 + qp * 8];
            }
            #pragma unroll
            for (int mt = 0; mt < 2; ++mt)
                #pragma unroll
                for (int nt = 0; nt < 4; ++nt)
                    acc[mt][nt] = __builtin_amdgcn_mfma_f32_16x16x32_bf16(
                        bfr[nt], areg[mt][kc], acc[mt][nt], 0, 0, 0);
        }
        const int n0g = nti * 128;
        #pragma unroll
        for (int nt = 0; nt < 4; ++nt) {
            int n0 = n0g + nw + nt * 16 + quad * 4;
            float4 b4 = *(const float4*)&bo[n0];
            #pragma unroll
            for (int mt = 0; mt < 2; ++mt) {
                int row = m0 + mw + mt * 16 + l16;
                if (row < kM) {
                    f32x4 a = acc[mt][nt];
                    float4 r4 = *(const float4*)(query + (size_t)row * N + n0);
                    float4 o;
                    o.x = a[0] + b4.x + r4.x;
                    o.y = a[1] + b4.y + r4.y;
                    o.z = a[2] + b4.z + r4.z;
                    o.w = a[3] + b4.w + r4.w;
                    *(float4*)(out + (size_t)row * N + n0) = o;
                }
            }
        }
    }
}

// ---------------------------------------------------------------------------
// Sampler v3b: one WAVE per query (2 per block), 4 channels/lane, dwordx2
// gathers (r7 math, proven correct). FIX vs r7: LDS laid out as
// sC[wave][corner][pt=16][head 8 + 2 pad] instead of [corner][unit].
//   phase-2 read (k2,pt fixed): head-groups at 8 B stride -> 8 distinct
//   bank-pairs, 8-lane broadcast within group -> conflict-free (r7: 128 B
//   stride = same bank pair for all 8 groups = 8-way conflict, 5.17M cnt).
//   phase-1 write: banks (8j+2h) mod 32 -> only 2-way aliasing (free).
// ---------------------------------------------------------------------------
struct C4 { int o[4]; float w[4]; };

__device__ __forceinline__ C4 mk_corners(float rx, float ry, float sx, float sy,
                                         float wgt, int lv, int h)
{
    C4 r;
    const int ww = cLW[lv], hh = cLH[lv];
    float x = rx * (float)ww + sx - 0.5f;
    float y = ry * (float)hh + sy - 0.5f;
    float xf = floorf(x), yf = floorf(y);
    int x0 = (int)xf, y0 = (int)yf;
    float wx1 = x - xf, wx0 = 1.f - wx1;
    float wy1 = y - yf, wy0 = 1.f - wy1;
    bool vx0 = (x0 >= 0) & (x0 < ww);
    bool vx1 = (x0 >= -1) & (x0 + 1 < ww);
    bool vy0 = (y0 >= 0) & (y0 < hh);
    bool vy1 = (y0 >= -1) & (y0 + 1 < hh);
    int cx0 = min(max(x0, 0), ww - 1);
    int cx1 = min(max(x0 + 1, 0), ww - 1);
    int cy0 = min(max(y0, 0), hh - 1);
    int cy1 = min(max(y0 + 1, 0), hh - 1);
    const int base2 = cLS[lv] * 512 + h * 64;                // BYTE offsets
    r.o[0] = base2 + (cy0 * ww + cx0) * 512; r.w[0] = (vx0 & vy0) ? wgt * wx0 * wy0 : 0.f;
    r.o[1] = base2 + (cy0 * ww + cx1) * 512; r.w[1] = (vx1 & vy0) ? wgt * wx1 * wy0 : 0.f;
    r.o[2] = base2 + (cy1 * ww + cx0) * 512; r.w[2] = (vx0 & vy1) ? wgt * wx0 * wy1 : 0.f;
    r.o[3] = base2 + (cy1 * ww + cx1) * 512; r.w[3] = (vx1 & vy1) ? wgt * wx1 * wy1 : 0.f;
    return r;
}

__global__ __launch_bounds__(128) void msda_sample(
    const __hip_bfloat16* __restrict__ v,     // (BS*NV, 256) bf16
    const __hip_bfloat16* __restrict__ soaw,  // (M, 384) bf16: so | logits
    const float* __restrict__ rp,             // (M, 4, 2)
    __hip_bfloat16* __restrict__ mid)         // (kMpad, 256) bf16
{
    const int wv = threadIdx.x >> 6;          // wave -> query
    const int l  = threadIdx.x & 63;
    const int bq = blockIdx.x * 2 + wv;       // kM even: always < kM
    const int b  = bq >= kNQ;

    __shared__ int2 sC[2][4][16][10];         // [wave][corner][pt][head+pad]

    {   // phase 1: units u0 = 2l, u1 = 2l+1  (u = h*16 + lp)
        const int j  = l & 7;                 // lp0 = 2j, lp1 = 2j+1
        const int u0 = 2 * l;
        const int h  = u0 >> 4;               // head, same for both units
        const int lv = (u0 & 15) >> 2;        // level, same for both units

        uint2 so2 = *(const uint2*)(const void*)(soaw + (size_t)bq * 384 + 2 * u0);
        unsigned lg2 = *(const unsigned*)(const void*)(soaw + (size_t)bq * 384 + 256 + u0);
        float logit0 = bflo(lg2), logit1 = bfhi(lg2);
        float2 rr = *(const float2*)(rp + (size_t)bq * 8 + lv * 2);

        float mx = fmaxf(logit0, logit1);
        #pragma unroll
        for (int s = 4; s >= 1; s >>= 1) mx = fmaxf(mx, __shfl_xor(mx, s, 8));
        float e0 = __expf(logit0 - mx), e1 = __expf(logit1 - mx);
        float sum = e0 + e1;
        #pragma unroll
        for (int s = 4; s >= 1; s >>= 1) sum += __shfl_xor(sum, s, 8);
        float inv = 1.f / sum;

        C4 ca = mk_corners(rr.x, rr.y, bflo(so2.x), bfhi(so2.x), e0 * inv, lv, h);
        C4 cb = mk_corners(rr.x, rr.y, bflo(so2.y), bfhi(so2.y), e1 * inv, lv, h);
        #pragma unroll
        for (int k2 = 0; k2 < 4; ++k2) {
            sC[wv][k2][2 * j][h]     = make_int2(ca.o[k2], __float_as_int(ca.w[k2]));
            sC[wv][k2][2 * j + 1][h] = make_int2(cb.o[k2], __float_as_int(cb.w[k2]));
        }
    }
    __syncthreads();

    // phase 2: lane = (head l>>3, channels (l&7)*4 .. +3)
    const int h2 = l >> 3, c0 = (l & 7) * 4;
    const char* vb = (const char*)v + (size_t)b * ((size_t)kNV * 512);  // uniform base
    const unsigned cb2 = (unsigned)(c0 * 2);
    f32x2 acc0 = {0.f, 0.f}, acc1 = {0.f, 0.f};
    #pragma unroll 4
    for (int pt = 0; pt < 16; ++pt) {
        #pragma unroll
        for (int k2 = 0; k2 < 4; ++k2) {
            int2 pw = sC[wv][k2][pt][h2];
            float wgt = __int_as_float(pw.y);
            uint2 u2 = *(const uint2*)(const void*)(vb + ((unsigned)pw.x + cb2));
            f32x2 w2; w2.x = wgt; w2.y = wgt;
            f32x2 lo; lo.x = bflo(u2.x); lo.y = bfhi(u2.x);
            f32x2 hi; hi.x = bflo(u2.y); hi.y = bfhi(u2.y);
            acc0 = lo * w2 + acc0;            // ffp-contract -> v_pk_fma_f32
            acc1 = hi * w2 + acc1;
        }
    }
    *(uint2*)(void*)(mid + (size_t)bq * 256 + h2 * 32 + c0) =
        make_uint2(pack2(acc0.x, acc0.y), pack2(acc1.x, acc1.y));
}

// ---------------------------------------------------------------------------
extern "C" void kernel_launch(void* const* d_in, const int* in_sizes, int n_in,
                              void* d_out, int out_size, void* d_ws, size_t ws_size,
                              hipStream_t stream)
{
    const float* query = (const float*)d_in[0];
    const float* value = (const float*)d_in[1];
    const float* rp    = (const float*)d_in[2];
    const float* Wv  = (const float*)d_in[5];
    const float* bv  = (const float*)d_in[6];
    const float* Wso = (const float*)d_in[7];
    const float* bso = (const float*)d_in[8];
    const float* Waw = (const float*)d_in[9];
    const float* baw = (const float*)d_in[10];
    const float* Wo  = (const float*)d_in[11];
    const float* bo  = (const float*)d_in[12];

    // d_out overlay: v_b bf16 (kM*512 B) in first half; dead before the
    // final GEMM rewrites all of d_out.
    unsigned short* v_b = (unsigned short*)d_out;

    // ws: soaw bf16 (kM*384) | mid_b bf16 (kMpad*256) | WvT | WsoawT | WoT | bias384
    char* p = (char*)d_ws;
    __hip_bfloat16* soaw  = (__hip_bfloat16*)p;  p += (size_t)kM * 384 * 2;
    unsigned short* mid_b = (unsigned short*)p;  p += (size_t)kMpad * 256 * 2;
    unsigned short* WvT    = (unsigned short*)p; p += 256 * 256 * 2;
    unsigned short* WsoawT = (unsigned short*)p; p += 384 * 256 * 2;
    unsigned short* WoT    = (unsigned short*)p; p += 256 * 256 * 2;
    float* bias384         = (float*)p;

    hipLaunchKernelGGL(prep_w, dim3(898), dim3(256), 0, stream,
                       Wv, Wso, Waw, Wo, bso, baw, WvT, WsoawT, WoT, bias384);

    hipLaunchKernelGGL(gemm_dual, dim3(2, kMT), dim3(256), 0, stream,
                       value, (const __hip_bfloat16*)WvT, bv, v_b,
                       query, (const __hip_bfloat16*)WsoawT, bias384,
                       (unsigned short*)soaw);

    hipLaunchKernelGGL(msda_sample, dim3(kM / 2), dim3(128), 0, stream,
                       (const __hip_bfloat16*)v_b, soaw, rp, (__hip_bfloat16*)mid_b);

    hipLaunchKernelGGL(gemm_final, dim3(1, kMT), dim3(256), 0, stream,
                       mid_b, (const __hip_bfloat16*)WoT, bo, query, (float*)d_out);
}